// Round 19
// baseline (34.463 us; speedup 1.0000x reference)
//
#include <hip/hip_runtime.h>
#include <hip/hip_fp16.h>

// DCNv2: B=2, CIN=COUT=64, H=W=128, DG=8, cpg=8, 3x3 s1 p1 d1
constexpr int BB = 2;
constexpr int CINc = 64;
constexpr int HWc = 128 * 128;
constexpr int OCOFFc = 216;   // DG*3*9 offset-conv channels
constexpr int XP = 130;       // padded spatial dim (halo of 1)

// workspace layout (bytes)
constexpr size_t XT_BYTES  = (size_t)BB * 8 * XP * XP * 8 * 2;   // per-(b,dg) planes, 16B/px
constexpr size_t WB1_OFF   = XT_BYTES;
constexpr size_t WB1_BYTES = (size_t)9 * 8 * 256 * 8 * 2;        // offset W [tap][cgrp][oc256][8ci] fp16
constexpr size_t WM_OFF    = WB1_OFF + WB1_BYTES;
constexpr size_t WM_BYTES  = (size_t)72 * 64 * 8 * 2;            // main W [slot=dg*9+tap][oc][8c] fp16
constexpr size_t WS_NEEDED = WM_OFF + WM_BYTES;                  // ~4.6 MB

typedef _Float16 f16x8 __attribute__((ext_vector_type(8)));
typedef float    f32x4 __attribute__((ext_vector_type(4)));

// ---------- K0: fused prep: x->planes, weight transforms, halo zero ----------
__global__ void prep_all(const float* __restrict__ x, const float* __restrict__ w_off,
                         const float* __restrict__ weight,
                         __half* __restrict__ xT, __half* __restrict__ wB1,
                         __half* __restrict__ wM2) {
    int bid = blockIdx.x;
    if (bid < 1024) {
        int site = bid * 256 + threadIdx.x;      // B*8*HW = 262144
        int pix = site & (HWc - 1);
        int bdg = site >> 14;
        int dg = bdg & 7, b = bdg >> 3;
        int y = pix >> 7, xc = pix & 127;
        const float* xp = x + (size_t)(b * CINc + dg * 8) * HWc + pix;
        __half2 h0 = __halves2half2(__float2half(xp[0 * HWc]), __float2half(xp[1 * HWc]));
        __half2 h1 = __halves2half2(__float2half(xp[2 * HWc]), __float2half(xp[3 * HWc]));
        __half2 h2 = __halves2half2(__float2half(xp[4 * HWc]), __float2half(xp[5 * HWc]));
        __half2 h3 = __halves2half2(__float2half(xp[6 * HWc]), __float2half(xp[7 * HWc]));
        __half2* o = reinterpret_cast<__half2*>(
            xT + (((size_t)(b * 8 + dg) * XP + y + 1) * XP + xc + 1) * 8);
        o[0] = h0; o[1] = h1; o[2] = h2; o[3] = h3;
        return;
    }
    int idx = (bid - 1024) * 256 + threadIdx.x;
    if (idx < 9 * 8 * 256 * 8) {
        // wB1[tap][cgrp][oc][ci]: fragment-major, coalesced for direct global B-reads
        int ci = idx & 7;
        int oc = (idx >> 3) & 255;
        int c  = (idx >> 11) & 7;
        int tap = idx >> 14;
        float v = (oc < OCOFFc) ? w_off[oc * 576 + (c * 8 + ci) * 9 + tap] : 0.f;
        wB1[idx] = __float2half(v);
    } else if (idx < 9 * 8 * 256 * 8 + 72 * 64 * 8) {
        int j = idx - 9 * 8 * 256 * 8;       // wM2[slot][oc][ci], slot = dg*9+tap
        int ci = j & 7;
        int oc = (j >> 3) & 63;
        int slot = j >> 9;
        int dg = slot / 9;
        int tap = slot - dg * 9;
        wM2[j] = __float2half(weight[oc * 576 + (dg * 8 + ci) * 9 + tap]);
    } else {
        int j2 = idx - (9 * 8 * 256 * 8 + 72 * 64 * 8);   // halo zero: 16 planes x 516 px
        if (j2 < 16 * 516) {
            int plane = j2 / 516;
            int p = j2 - plane * 516;
            int y, xx;
            if (p < 130)      { y = 0;           xx = p; }
            else if (p < 260) { y = 129;         xx = p - 130; }
            else if (p < 388) { y = 1 + p - 260; xx = 0; }
            else              { y = 1 + p - 388; xx = 129; }
            uint4 z = {0u, 0u, 0u, 0u};
            *reinterpret_cast<uint4*>(xT + (((size_t)plane * XP + y) * XP + xx) * 8) = z;
        }
    }
}

// Phase B chunk issue for chunk CC_ (slots CC_*4+lh, all lanes useful):
// bf loads FIRST (LDS for slot<36 via LDSW, else global), then b64 offs read,
// addr math, 4 corner gathers.
#define DCN_IC(CC_, BF, G, W, LDSW)                                            \
  {                                                                            \
    const int slot_ = (CC_) * 4 + lh;                                          \
    if (LDSW) {                                                                \
      _Pragma("unroll")                                                        \
      for (int n_ = 0; n_ < 4; ++n_)                                           \
        BF[n_] = *reinterpret_cast<const f16x8*>(                              \
            wMl + ((size_t)slot_ * 64 + n_ * 16 + l15) * 8);                   \
    } else {                                                                   \
      _Pragma("unroll")                                                        \
      for (int n_ = 0; n_ < 4; ++n_)                                           \
        BF[n_] = *reinterpret_cast<const f16x8*>(                              \
            wM2 + ((size_t)slot_ * 64 + n_ * 16 + l15) * 8);                   \
    }                                                                          \
    const int dgc_ = slot_ / 9;                                                \
    const int tap_ = slot_ - dgc_ * 9;                                         \
    uint2 ov_ = *reinterpret_cast<const uint2*>(                               \
        offsb + ((size_t)(dgc_ * 128 + px)) * 36 + tap_ * 4);                  \
    __half2 p0_ = *reinterpret_cast<const __half2*>(&ov_.x);                   \
    __half2 p1_ = *reinterpret_cast<const __half2*>(&ov_.y);                   \
    float oy_ = __half2float(__low2half(p0_));                                 \
    float ox_ = __half2float(__high2half(p0_));                                \
    float mk_ = __half2float(__low2half(p1_));                                 \
    const int ki_ = tap_ / 3, kj_ = tap_ - ki_ * 3;                            \
    float sy_ = oy_ + (float)(gy - 1 + ki_);                                   \
    float sx_ = ox_ + (float)(gx - 1 + kj_);                                   \
    float y0f_ = floorf(sy_), x0f_ = floorf(sx_);                              \
    int iy0_ = (int)y0f_, ix0_ = (int)x0f_;                                    \
    float ly_ = sy_ - y0f_, lx_ = sx_ - x0f_;                                  \
    float hy_ = 1.f - ly_, hx_ = 1.f - lx_;                                    \
    float vy0_ = ((unsigned)iy0_ < 128u) ? 1.f : 0.f;                          \
    float vy1_ = ((unsigned)(iy0_ + 1) < 128u) ? 1.f : 0.f;                    \
    float vx0_ = ((unsigned)ix0_ < 128u) ? 1.f : 0.f;                          \
    float vx1_ = ((unsigned)(ix0_ + 1) < 128u) ? 1.f : 0.f;                    \
    W[0] = __floats2half2_rn(hy_ * hx_ * vy0_ * vx0_ * mk_,                    \
                             hy_ * lx_ * vy0_ * vx1_ * mk_);                   \
    W[1] = __floats2half2_rn(ly_ * hx_ * vy1_ * vx0_ * mk_,                    \
                             ly_ * lx_ * vy1_ * vx1_ * mk_);                   \
    int y0c_ = min(max(iy0_, 0), 127), y1c_ = min(max(iy0_ + 1, 0), 127);      \
    int x0c_ = min(max(ix0_, 0), 127), x1c_ = min(max(ix0_ + 1, 0), 127);      \
    const __half* xb_ = xT + (size_t)(b * 8 + dgc_) * XP * XP * 8;             \
    G[0] = *reinterpret_cast<const float4*>(xb_ + ((size_t)(y0c_ + 1) * XP + x0c_ + 1) * 8); \
    G[1] = *reinterpret_cast<const float4*>(xb_ + ((size_t)(y0c_ + 1) * XP + x1c_ + 1) * 8); \
    G[2] = *reinterpret_cast<const float4*>(xb_ + ((size_t)(y1c_ + 1) * XP + x0c_ + 1) * 8); \
    G[3] = *reinterpret_cast<const float4*>(xb_ + ((size_t)(y1c_ + 1) * XP + x1c_ + 1) * 8); \
  }

// Phase B chunk consume: blend -> af, 4 MFMAs.
#define DCN_CC(BF, G, W)                                                       \
  {                                                                            \
    __half2 W00_ = __half2half2(__low2half(W[0]));                             \
    __half2 W01_ = __half2half2(__high2half(W[0]));                            \
    __half2 W10_ = __half2half2(__low2half(W[1]));                             \
    __half2 W11_ = __half2half2(__high2half(W[1]));                            \
    const __half2* a00_ = reinterpret_cast<const __half2*>(&G[0]);             \
    const __half2* a01_ = reinterpret_cast<const __half2*>(&G[1]);             \
    const __half2* a10_ = reinterpret_cast<const __half2*>(&G[2]);             \
    const __half2* a11_ = reinterpret_cast<const __half2*>(&G[3]);             \
    __align__(16) __half2 rr_[4];                                              \
    _Pragma("unroll")                                                          \
    for (int cc_ = 0; cc_ < 4; ++cc_)                                          \
      rr_[cc_] = __hfma2(a00_[cc_], W00_,                                      \
                 __hfma2(a01_[cc_], W01_,                                      \
                 __hfma2(a10_[cc_], W10_, __hmul2(a11_[cc_], W11_))));         \
    f16x8 af_ = *reinterpret_cast<const f16x8*>(rr_);                          \
    _Pragma("unroll")                                                          \
    for (int n_ = 0; n_ < 4; ++n_)                                             \
      acc2[n_] = __builtin_amdgcn_mfma_f32_16x16x32_f16(                       \
          af_, BF[n_], acc2[n_], 0, 0, 0);                                     \
  }

// ---------- Fused DCN: 128px tile, 512 thr, grid 256, XCD swizzle ----------
// Phase A: r10 structure; full tap unroll; wc==3 waves skip the all-zero
//          oc 224-255 fragments (-12.5% Phase-A MFMA + bf TA).
// Phase B: flattened 72-slot K; 3-deep chunk pipeline (issue-to-consume
//          distance ~2 chunks to cover L2 gather latency).
__global__ __launch_bounds__(512, 2) void dcn_fused_k(
        const __half* __restrict__ xT, const __half* __restrict__ wB1,
        const float* __restrict__ cob, const __half* __restrict__ wM2,
        const float* __restrict__ bias, float* __restrict__ out) {
    __shared__ __half xs[1440 * 8];        // 23040 B: [row10][col18][sl8][8ch]
    __shared__ __half offsb[8 * 128 * 36]; // 73728 B: [dg][px][tap9][4: oy,ox,m,pad]
    __shared__ __half wMl[36 * 64 * 8];    // 36864 B: wM2 slots 0-35
    const int tid = threadIdx.x;
    // XCD-aware swizzle: each XCD gets 32 consecutive vids = 4 contiguous row-bands
    const int fid = blockIdx.x + (blockIdx.y << 3) + (blockIdx.z << 7);
    const int vid = ((fid & 7) << 5) + (fid >> 3);
    const int bx = vid & 7;               // 0..7   (16 px wide)
    const int by = (vid >> 3) & 15;       // 0..15  (8 px tall)
    const int b  = vid >> 7;

    // ---- staging: x patch (rows by*8..+9, cols bx*16..+17) + wM2 slots 0-35 ----
    #pragma unroll
    for (int it = 0; it < 3; ++it) {
        int idx = tid + it * 512;
        if (idx < 1440) {
            int yl = idx / 144;                  // 144 = 18 cols * 8 slots
            int rem = idx - yl * 144;
            int cl = rem >> 3, sl = rem & 7;
            int dg = sl ^ (cl & 7);
            float4 v = *reinterpret_cast<const float4*>(
                xT + (((size_t)(b * 8 + dg) * XP + by * 8 + yl) * XP + bx * 16 + cl) * 8);
            *reinterpret_cast<float4*>(xs + idx * 8) = v;
        }
    }
    #pragma unroll
    for (int i = 0; i < 5; ++i) {              // 2304 float4 = 36864 B
        int idx = tid + i * 512;
        if (idx < 2304)
            *reinterpret_cast<float4*>(wMl + (size_t)idx * 8) =
                *reinterpret_cast<const float4*>(wM2 + (size_t)idx * 8);
    }
    __syncthreads();   // barrier 1: xs + wMl ready (read-only hereafter)

    const int lane = tid & 63;
    const int wid = tid >> 6;
    const int l15 = lane & 15, lh = lane >> 4;

    {   // ---- Phase A: 9-tap implicit GEMM, NO barriers; bf direct from global ----
        const int wr = wid & 1;            // px half (4 image rows)
        const int wc = wid >> 1;           // oc quarter (64 of 256)
        const bool full = (wc < 3);        // wc==3: oc 216-255 mostly zero-padded
        f32x4 acc[4][4];
        const f32x4 zero = {0.f, 0.f, 0.f, 0.f};
        #pragma unroll
        for (int ty = 0; ty < 4; ++ty)
            #pragma unroll
            for (int ot = 0; ot < 4; ++ot) acc[ty][ot] = zero;

        #pragma unroll
        for (int tap = 0; tap < 9; ++tap) {
            const int r = tap / 3, s = tap - r * 3;
            const int j = l15 + s;                    // patch col
            #pragma unroll
            for (int h = 0; h < 2; ++h) {
                const int c = h * 4 + lh;             // cin group 0..7
                const int sl = c ^ (j & 7);
                f16x8 af[4], bf[4];
                #pragma unroll
                for (int ot = 0; ot < 2; ++ot) {
                    int oc = wc * 64 + ot * 16 + l15;
                    bf[ot] = *reinterpret_cast<const f16x8*>(
                        wB1 + (size_t)(((tap * 8 + c) * 256 + oc)) * 8);
                }
                if (full) {
                    #pragma unroll
                    for (int ot = 2; ot < 4; ++ot) {
                        int oc = wc * 64 + ot * 16 + l15;
                        bf[ot] = *reinterpret_cast<const f16x8*>(
                            wB1 + (size_t)(((tap * 8 + c) * 256 + oc)) * 8);
                    }
                }
                #pragma unroll
                for (int ty = 0; ty < 4; ++ty) {
                    int row = wr * 4 + ty + r;
                    af[ty] = *reinterpret_cast<const f16x8*>(xs + (row * 18 + j) * 64 + sl * 8);
                }
                #pragma unroll
                for (int ty = 0; ty < 4; ++ty)
                    #pragma unroll
                    for (int ot = 0; ot < 2; ++ot)
                        acc[ty][ot] = __builtin_amdgcn_mfma_f32_16x16x32_f16(
                            af[ty], bf[ot], acc[ty][ot], 0, 0, 0);
                if (full) {
                    #pragma unroll
                    for (int ty = 0; ty < 4; ++ty)
                        #pragma unroll
                        for (int ot = 2; ot < 4; ++ot)
                            acc[ty][ot] = __builtin_amdgcn_mfma_f32_16x16x32_f16(
                                af[ty], bf[ot], acc[ty][ot], 0, 0, 0);
                }
            }
        }

        // ---- Phase A epilogue -> offsb[dg][px][k*4+comp] ----
        #pragma unroll
        for (int ot = 0; ot < 4; ++ot) {
            int oc = wc * 64 + ot * 16 + l15;
            if (oc < OCOFFc) {
                float bi = cob[oc];
                bool sig = (oc >= 144);
                int dg, k, comp;
                if (oc < 144) { dg = oc / 18; int rem = oc - dg * 18; k = rem >> 1; comp = rem & 1; }
                else          { int mm = oc - 144; dg = mm / 9; k = mm - dg * 9; comp = 2; }
                #pragma unroll
                for (int ty = 0; ty < 4; ++ty) {
                    int pxw = (wr * 4 + ty) * 16 + lh * 4;
                    float v0 = acc[ty][ot][0] + bi, v1 = acc[ty][ot][1] + bi;
                    float v2 = acc[ty][ot][2] + bi, v3 = acc[ty][ot][3] + bi;
                    if (sig) {
                        v0 = 1.f / (1.f + __expf(-v0)); v1 = 1.f / (1.f + __expf(-v1));
                        v2 = 1.f / (1.f + __expf(-v2)); v3 = 1.f / (1.f + __expf(-v3));
                    }
                    size_t base = (size_t)(dg * 128) * 36 + k * 4 + comp;
                    offsb[base + (size_t)(pxw + 0) * 36] = __float2half(v0);
                    offsb[base + (size_t)(pxw + 1) * 36] = __float2half(v1);
                    offsb[base + (size_t)(pxw + 2) * 36] = __float2half(v2);
                    offsb[base + (size_t)(pxw + 3) * 36] = __float2half(v3);
                }
            }
        }
    }
    __syncthreads();   // barrier 2: offsb complete

    // ---- Phase B: wave = image row; 18 flattened chunks, 3-deep pipeline ----
    const int px = wid * 16 + l15;    // offsb px index
    const int gy = by * 8 + wid;
    const int gx = bx * 16 + l15;

    f32x4 acc2[4];
    const f32x4 zero2 = {0.f, 0.f, 0.f, 0.f};
    #pragma unroll
    for (int n = 0; n < 4; ++n) acc2[n] = zero2;

    f16x8 bfX[4], bfY[4], bfZ[4];
    float4 gX[4], gY[4], gZ[4];
    __half2 wX[2], wY[2], wZ[2];

    DCN_IC(0,  bfX, gX, wX, true);
    DCN_IC(1,  bfY, gY, wY, true);
    DCN_IC(2,  bfZ, gZ, wZ, true);   DCN_CC(bfX, gX, wX);
    DCN_IC(3,  bfX, gX, wX, true);   DCN_CC(bfY, gY, wY);
    DCN_IC(4,  bfY, gY, wY, true);   DCN_CC(bfZ, gZ, wZ);
    DCN_IC(5,  bfZ, gZ, wZ, true);   DCN_CC(bfX, gX, wX);
    DCN_IC(6,  bfX, gX, wX, true);   DCN_CC(bfY, gY, wY);
    DCN_IC(7,  bfY, gY, wY, true);   DCN_CC(bfZ, gZ, wZ);
    DCN_IC(8,  bfZ, gZ, wZ, true);   DCN_CC(bfX, gX, wX);
    DCN_IC(9,  bfX, gX, wX, false);  DCN_CC(bfY, gY, wY);
    DCN_IC(10, bfY, gY, wY, false);  DCN_CC(bfZ, gZ, wZ);
    DCN_IC(11, bfZ, gZ, wZ, false);  DCN_CC(bfX, gX, wX);
    DCN_IC(12, bfX, gX, wX, false);  DCN_CC(bfY, gY, wY);
    DCN_IC(13, bfY, gY, wY, false);  DCN_CC(bfZ, gZ, wZ);
    DCN_IC(14, bfZ, gZ, wZ, false);  DCN_CC(bfX, gX, wX);
    DCN_IC(15, bfX, gX, wX, false);  DCN_CC(bfY, gY, wY);
    DCN_IC(16, bfY, gY, wY, false);  DCN_CC(bfZ, gZ, wZ);
    DCN_IC(17, bfZ, gZ, wZ, false);  DCN_CC(bfX, gX, wX);
    DCN_CC(bfY, gY, wY);
    DCN_CC(bfZ, gZ, wZ);

    // ---- store: D row -> x-offset (lh*4+reg), col -> oc (n*16+l15) ----
    #pragma unroll
    for (int n = 0; n < 4; ++n) {
        int oc = n * 16 + l15;
        float bi = bias[oc];
        float4 v = make_float4(acc2[n][0] + bi, acc2[n][1] + bi,
                               acc2[n][2] + bi, acc2[n][3] + bi);
        *reinterpret_cast<float4*>(
            out + (size_t)(b * 64 + oc) * HWc + gy * 128 + bx * 16 + lh * 4) = v;
    }
}

extern "C" void kernel_launch(void* const* d_in, const int* in_sizes, int n_in,
                              void* d_out, int out_size, void* d_ws, size_t ws_size,
                              hipStream_t stream) {
    const float* x      = (const float*)d_in[0];
    const float* w_off  = (const float*)d_in[1];
    const float* cob    = (const float*)d_in[2];
    const float* weight = (const float*)d_in[3];
    const float* bias   = (const float*)d_in[4];
    float* out = (float*)d_out;
    if (ws_size < WS_NEEDED) return;

    char* ws = (char*)d_ws;
    __half* xT  = (__half*)ws;
    __half* wB1 = (__half*)(ws + WB1_OFF);
    __half* wM2 = (__half*)(ws + WM_OFF);

    prep_all<<<1777, 256, 0, stream>>>(x, w_off, weight, xT, wB1, wM2);
    dcn_fused_k<<<dim3(8, 16, 2), 512, 0, stream>>>(xT, wB1, cob, wM2, bias, out);
}

// Round 20
// 34.063 us; speedup vs baseline: 1.0117x; 1.0117x over previous
//
#include <hip/hip_runtime.h>
#include <hip/hip_fp16.h>

// DCNv2: B=2, CIN=COUT=64, H=W=128, DG=8, cpg=8, 3x3 s1 p1 d1
constexpr int BB = 2;
constexpr int CINc = 64;
constexpr int HWc = 128 * 128;
constexpr int OCOFFc = 216;   // DG*3*9 offset-conv channels
constexpr int XP = 130;       // padded spatial dim (halo of 1)

// workspace layout (bytes)
constexpr size_t XT_BYTES  = (size_t)BB * 8 * XP * XP * 8 * 2;   // per-(b,dg) planes, 16B/px
constexpr size_t WB1_OFF   = XT_BYTES;
constexpr size_t WB1_BYTES = (size_t)9 * 8 * 256 * 8 * 2;        // offset W [tap][cgrp][oc256][8ci] fp16
constexpr size_t WM_OFF    = WB1_OFF + WB1_BYTES;
constexpr size_t WM_BYTES  = (size_t)72 * 64 * 8 * 2;            // main W [slot=dg*9+tap][oc][8c] fp16
constexpr size_t WS_NEEDED = WM_OFF + WM_BYTES;                  // ~4.6 MB

typedef _Float16 f16x8 __attribute__((ext_vector_type(8)));
typedef float    f32x4 __attribute__((ext_vector_type(4)));

// ---------- K0: fused prep: x->planes, weight transforms, halo zero ----------
__global__ void prep_all(const float* __restrict__ x, const float* __restrict__ w_off,
                         const float* __restrict__ weight,
                         __half* __restrict__ xT, __half* __restrict__ wB1,
                         __half* __restrict__ wM2) {
    int bid = blockIdx.x;
    if (bid < 1024) {
        int site = bid * 256 + threadIdx.x;      // B*8*HW = 262144
        int pix = site & (HWc - 1);
        int bdg = site >> 14;
        int dg = bdg & 7, b = bdg >> 3;
        int y = pix >> 7, xc = pix & 127;
        const float* xp = x + (size_t)(b * CINc + dg * 8) * HWc + pix;
        __half2 h0 = __halves2half2(__float2half(xp[0 * HWc]), __float2half(xp[1 * HWc]));
        __half2 h1 = __halves2half2(__float2half(xp[2 * HWc]), __float2half(xp[3 * HWc]));
        __half2 h2 = __halves2half2(__float2half(xp[4 * HWc]), __float2half(xp[5 * HWc]));
        __half2 h3 = __halves2half2(__float2half(xp[6 * HWc]), __float2half(xp[7 * HWc]));
        __half2* o = reinterpret_cast<__half2*>(
            xT + (((size_t)(b * 8 + dg) * XP + y + 1) * XP + xc + 1) * 8);
        o[0] = h0; o[1] = h1; o[2] = h2; o[3] = h3;
        return;
    }
    int idx = (bid - 1024) * 256 + threadIdx.x;
    if (idx < 9 * 8 * 256 * 8) {
        // wB1[tap][cgrp][oc][ci]: fragment-major, coalesced for direct global B-reads
        int ci = idx & 7;
        int oc = (idx >> 3) & 255;
        int c  = (idx >> 11) & 7;
        int tap = idx >> 14;
        float v = (oc < OCOFFc) ? w_off[oc * 576 + (c * 8 + ci) * 9 + tap] : 0.f;
        wB1[idx] = __float2half(v);
    } else if (idx < 9 * 8 * 256 * 8 + 72 * 64 * 8) {
        int j = idx - 9 * 8 * 256 * 8;       // wM2[slot][oc][ci], slot = dg*9+tap
        int ci = j & 7;
        int oc = (j >> 3) & 63;
        int slot = j >> 9;
        int dg = slot / 9;
        int tap = slot - dg * 9;
        wM2[j] = __float2half(weight[oc * 576 + (dg * 8 + ci) * 9 + tap]);
    } else {
        int j2 = idx - (9 * 8 * 256 * 8 + 72 * 64 * 8);   // halo zero: 16 planes x 516 px
        if (j2 < 16 * 516) {
            int plane = j2 / 516;
            int p = j2 - plane * 516;
            int y, xx;
            if (p < 130)      { y = 0;           xx = p; }
            else if (p < 260) { y = 129;         xx = p - 130; }
            else if (p < 388) { y = 1 + p - 260; xx = 0; }
            else              { y = 1 + p - 388; xx = 129; }
            uint4 z = {0u, 0u, 0u, 0u};
            *reinterpret_cast<uint4*>(xT + (((size_t)plane * XP + y) * XP + xx) * 8) = z;
        }
    }
}

// Phase B chunk issue for chunk CC_ (slots CC_*4+lh, all lanes useful):
// bf loads FIRST (LDS for slot<36 via LDSW, else global), then b64 offs read,
// addr math, 4 corner gathers.
#define DCN_IC(CC_, BF, G, W, LDSW)                                            \
  {                                                                            \
    const int slot_ = (CC_) * 4 + lh;                                          \
    if (LDSW) {                                                                \
      _Pragma("unroll")                                                        \
      for (int n_ = 0; n_ < 4; ++n_)                                           \
        BF[n_] = *reinterpret_cast<const f16x8*>(                              \
            wMl + ((size_t)slot_ * 64 + n_ * 16 + l15) * 8);                   \
    } else {                                                                   \
      _Pragma("unroll")                                                        \
      for (int n_ = 0; n_ < 4; ++n_)                                           \
        BF[n_] = *reinterpret_cast<const f16x8*>(                              \
            wM2 + ((size_t)slot_ * 64 + n_ * 16 + l15) * 8);                   \
    }                                                                          \
    const int dgc_ = slot_ / 9;                                                \
    const int tap_ = slot_ - dgc_ * 9;                                         \
    uint2 ov_ = *reinterpret_cast<const uint2*>(                               \
        offsb + ((size_t)(dgc_ * 128 + px)) * 36 + tap_ * 4);                  \
    __half2 p0_ = *reinterpret_cast<const __half2*>(&ov_.x);                   \
    __half2 p1_ = *reinterpret_cast<const __half2*>(&ov_.y);                   \
    float oy_ = __half2float(__low2half(p0_));                                 \
    float ox_ = __half2float(__high2half(p0_));                                \
    float mk_ = __half2float(__low2half(p1_));                                 \
    const int ki_ = tap_ / 3, kj_ = tap_ - ki_ * 3;                            \
    float sy_ = oy_ + (float)(gy - 1 + ki_);                                   \
    float sx_ = ox_ + (float)(gx - 1 + kj_);                                   \
    float y0f_ = floorf(sy_), x0f_ = floorf(sx_);                              \
    int iy0_ = (int)y0f_, ix0_ = (int)x0f_;                                    \
    float ly_ = sy_ - y0f_, lx_ = sx_ - x0f_;                                  \
    float hy_ = 1.f - ly_, hx_ = 1.f - lx_;                                    \
    float vy0_ = ((unsigned)iy0_ < 128u) ? 1.f : 0.f;                          \
    float vy1_ = ((unsigned)(iy0_ + 1) < 128u) ? 1.f : 0.f;                    \
    float vx0_ = ((unsigned)ix0_ < 128u) ? 1.f : 0.f;                          \
    float vx1_ = ((unsigned)(ix0_ + 1) < 128u) ? 1.f : 0.f;                    \
    W[0] = __floats2half2_rn(hy_ * hx_ * vy0_ * vx0_ * mk_,                    \
                             hy_ * lx_ * vy0_ * vx1_ * mk_);                   \
    W[1] = __floats2half2_rn(ly_ * hx_ * vy1_ * vx0_ * mk_,                    \
                             ly_ * lx_ * vy1_ * vx1_ * mk_);                   \
    int y0c_ = min(max(iy0_, 0), 127), y1c_ = min(max(iy0_ + 1, 0), 127);      \
    int x0c_ = min(max(ix0_, 0), 127), x1c_ = min(max(ix0_ + 1, 0), 127);      \
    const __half* xb_ = xT + (size_t)(b * 8 + dgc_) * XP * XP * 8;             \
    G[0] = *reinterpret_cast<const float4*>(xb_ + ((size_t)(y0c_ + 1) * XP + x0c_ + 1) * 8); \
    G[1] = *reinterpret_cast<const float4*>(xb_ + ((size_t)(y0c_ + 1) * XP + x1c_ + 1) * 8); \
    G[2] = *reinterpret_cast<const float4*>(xb_ + ((size_t)(y1c_ + 1) * XP + x0c_ + 1) * 8); \
    G[3] = *reinterpret_cast<const float4*>(xb_ + ((size_t)(y1c_ + 1) * XP + x1c_ + 1) * 8); \
  }

// Phase B chunk consume: blend -> af, 4 MFMAs.
#define DCN_CC(BF, G, W)                                                       \
  {                                                                            \
    __half2 W00_ = __half2half2(__low2half(W[0]));                             \
    __half2 W01_ = __half2half2(__high2half(W[0]));                            \
    __half2 W10_ = __half2half2(__low2half(W[1]));                             \
    __half2 W11_ = __half2half2(__high2half(W[1]));                            \
    const __half2* a00_ = reinterpret_cast<const __half2*>(&G[0]);             \
    const __half2* a01_ = reinterpret_cast<const __half2*>(&G[1]);             \
    const __half2* a10_ = reinterpret_cast<const __half2*>(&G[2]);             \
    const __half2* a11_ = reinterpret_cast<const __half2*>(&G[3]);             \
    __align__(16) __half2 rr_[4];                                              \
    _Pragma("unroll")                                                          \
    for (int cc_ = 0; cc_ < 4; ++cc_)                                          \
      rr_[cc_] = __hfma2(a00_[cc_], W00_,                                      \
                 __hfma2(a01_[cc_], W01_,                                      \
                 __hfma2(a10_[cc_], W10_, __hmul2(a11_[cc_], W11_))));         \
    f16x8 af_ = *reinterpret_cast<const f16x8*>(rr_);                          \
    _Pragma("unroll")                                                          \
    for (int n_ = 0; n_ < 4; ++n_)                                             \
      acc2[n_] = __builtin_amdgcn_mfma_f32_16x16x32_f16(                       \
          af_, BF[n_], acc2[n_], 0, 0, 0);                                     \
  }

// ---------- Fused DCN: 128px tile, 512 thr, grid 256, XCD swizzle ----------
// Phase A: r10 structure (bf direct from global, no weight LDS, no tap barriers).
// Phase B: flattened 72-slot K over (dg,tap) -> 18 chunks, zero padding waste;
//          chunk-pipelined; wM2 slots 0-35 from LDS, 36-71 from global.
__global__ __launch_bounds__(512, 2) void dcn_fused_k(
        const __half* __restrict__ xT, const __half* __restrict__ wB1,
        const float* __restrict__ cob, const __half* __restrict__ wM2,
        const float* __restrict__ bias, float* __restrict__ out) {
    __shared__ __half xs[1440 * 8];        // 23040 B: [row10][col18][sl8][8ch]
    __shared__ __half offsb[8 * 128 * 36]; // 73728 B: [dg][px][tap9][4: oy,ox,m,pad]
    __shared__ __half wMl[36 * 64 * 8];    // 36864 B: wM2 slots 0-35
    const int tid = threadIdx.x;
    // XCD-aware swizzle: each XCD gets 32 consecutive vids = 4 contiguous row-bands
    const int fid = blockIdx.x + (blockIdx.y << 3) + (blockIdx.z << 7);
    const int vid = ((fid & 7) << 5) + (fid >> 3);
    const int bx = vid & 7;               // 0..7   (16 px wide)
    const int by = (vid >> 3) & 15;       // 0..15  (8 px tall)
    const int b  = vid >> 7;

    // ---- staging: x patch (rows by*8..+9, cols bx*16..+17) + wM2 slots 0-35 ----
    #pragma unroll
    for (int it = 0; it < 3; ++it) {
        int idx = tid + it * 512;
        if (idx < 1440) {
            int yl = idx / 144;                  // 144 = 18 cols * 8 slots
            int rem = idx - yl * 144;
            int cl = rem >> 3, sl = rem & 7;
            int dg = sl ^ (cl & 7);
            float4 v = *reinterpret_cast<const float4*>(
                xT + (((size_t)(b * 8 + dg) * XP + by * 8 + yl) * XP + bx * 16 + cl) * 8);
            *reinterpret_cast<float4*>(xs + idx * 8) = v;
        }
    }
    #pragma unroll
    for (int i = 0; i < 5; ++i) {              // 2304 float4 = 36864 B
        int idx = tid + i * 512;
        if (idx < 2304)
            *reinterpret_cast<float4*>(wMl + (size_t)idx * 8) =
                *reinterpret_cast<const float4*>(wM2 + (size_t)idx * 8);
    }
    __syncthreads();   // barrier 1: xs + wMl ready (read-only hereafter)

    const int lane = tid & 63;
    const int wid = tid >> 6;
    const int l15 = lane & 15, lh = lane >> 4;

    {   // ---- Phase A: 9-tap implicit GEMM, NO barriers; bf direct from global ----
        const int wr = wid & 1;            // px half (4 image rows)
        const int wc = wid >> 1;           // oc quarter (64 of 256)
        f32x4 acc[4][4];
        const f32x4 zero = {0.f, 0.f, 0.f, 0.f};
        #pragma unroll
        for (int ty = 0; ty < 4; ++ty)
            #pragma unroll
            for (int ot = 0; ot < 4; ++ot) acc[ty][ot] = zero;

        #pragma unroll 3
        for (int tap = 0; tap < 9; ++tap) {
            const int r = tap / 3, s = tap - r * 3;
            const int j = l15 + s;                    // patch col
            #pragma unroll
            for (int h = 0; h < 2; ++h) {
                const int c = h * 4 + lh;             // cin group 0..7
                const int sl = c ^ (j & 7);
                f16x8 af[4], bf[4];
                #pragma unroll
                for (int ot = 0; ot < 4; ++ot) {
                    int oc = wc * 64 + ot * 16 + l15;
                    bf[ot] = *reinterpret_cast<const f16x8*>(
                        wB1 + (size_t)(((tap * 8 + c) * 256 + oc)) * 8);
                }
                #pragma unroll
                for (int ty = 0; ty < 4; ++ty) {
                    int row = wr * 4 + ty + r;
                    af[ty] = *reinterpret_cast<const f16x8*>(xs + (row * 18 + j) * 64 + sl * 8);
                }
                #pragma unroll
                for (int ty = 0; ty < 4; ++ty)
                    #pragma unroll
                    for (int ot = 0; ot < 4; ++ot)
                        acc[ty][ot] = __builtin_amdgcn_mfma_f32_16x16x32_f16(
                            af[ty], bf[ot], acc[ty][ot], 0, 0, 0);
            }
        }

        // ---- Phase A epilogue -> offsb[dg][px][k*4+comp] ----
        #pragma unroll
        for (int ot = 0; ot < 4; ++ot) {
            int oc = wc * 64 + ot * 16 + l15;
            if (oc < OCOFFc) {
                float bi = cob[oc];
                bool sig = (oc >= 144);
                int dg, k, comp;
                if (oc < 144) { dg = oc / 18; int rem = oc - dg * 18; k = rem >> 1; comp = rem & 1; }
                else          { int mm = oc - 144; dg = mm / 9; k = mm - dg * 9; comp = 2; }
                #pragma unroll
                for (int ty = 0; ty < 4; ++ty) {
                    int pxw = (wr * 4 + ty) * 16 + lh * 4;
                    float v0 = acc[ty][ot][0] + bi, v1 = acc[ty][ot][1] + bi;
                    float v2 = acc[ty][ot][2] + bi, v3 = acc[ty][ot][3] + bi;
                    if (sig) {
                        v0 = 1.f / (1.f + __expf(-v0)); v1 = 1.f / (1.f + __expf(-v1));
                        v2 = 1.f / (1.f + __expf(-v2)); v3 = 1.f / (1.f + __expf(-v3));
                    }
                    size_t base = (size_t)(dg * 128) * 36 + k * 4 + comp;
                    offsb[base + (size_t)(pxw + 0) * 36] = __float2half(v0);
                    offsb[base + (size_t)(pxw + 1) * 36] = __float2half(v1);
                    offsb[base + (size_t)(pxw + 2) * 36] = __float2half(v2);
                    offsb[base + (size_t)(pxw + 3) * 36] = __float2half(v3);
                }
            }
        }
    }
    __syncthreads();   // barrier 2: offsb complete

    // ---- Phase B: wave = image row; 18 flattened chunks, ping-pong pipeline ----
    const int px = wid * 16 + l15;    // offsb px index
    const int gy = by * 8 + wid;
    const int gx = bx * 16 + l15;

    f32x4 acc2[4];
    const f32x4 zero2 = {0.f, 0.f, 0.f, 0.f};
    #pragma unroll
    for (int n = 0; n < 4; ++n) acc2[n] = zero2;

    f16x8 bfX[4], bfY[4];
    float4 gX[4], gY[4];
    __half2 wX[2], wY[2];

    DCN_IC(0,  bfX, gX, wX, true);
    DCN_IC(1,  bfY, gY, wY, true);   DCN_CC(bfX, gX, wX);
    DCN_IC(2,  bfX, gX, wX, true);   DCN_CC(bfY, gY, wY);
    DCN_IC(3,  bfY, gY, wY, true);   DCN_CC(bfX, gX, wX);
    DCN_IC(4,  bfX, gX, wX, true);   DCN_CC(bfY, gY, wY);
    DCN_IC(5,  bfY, gY, wY, true);   DCN_CC(bfX, gX, wX);
    DCN_IC(6,  bfX, gX, wX, true);   DCN_CC(bfY, gY, wY);
    DCN_IC(7,  bfY, gY, wY, true);   DCN_CC(bfX, gX, wX);
    DCN_IC(8,  bfX, gX, wX, true);   DCN_CC(bfY, gY, wY);
    DCN_IC(9,  bfY, gY, wY, false);  DCN_CC(bfX, gX, wX);
    DCN_IC(10, bfX, gX, wX, false);  DCN_CC(bfY, gY, wY);
    DCN_IC(11, bfY, gY, wY, false);  DCN_CC(bfX, gX, wX);
    DCN_IC(12, bfX, gX, wX, false);  DCN_CC(bfY, gY, wY);
    DCN_IC(13, bfY, gY, wY, false);  DCN_CC(bfX, gX, wX);
    DCN_IC(14, bfX, gX, wX, false);  DCN_CC(bfY, gY, wY);
    DCN_IC(15, bfY, gY, wY, false);  DCN_CC(bfX, gX, wX);
    DCN_IC(16, bfX, gX, wX, false);  DCN_CC(bfY, gY, wY);
    DCN_IC(17, bfY, gY, wY, false);  DCN_CC(bfX, gX, wX);
    DCN_CC(bfY, gY, wY);

    // ---- store: D row -> x-offset (lh*4+reg), col -> oc (n*16+l15) ----
    #pragma unroll
    for (int n = 0; n < 4; ++n) {
        int oc = n * 16 + l15;
        float bi = bias[oc];
        float4 v = make_float4(acc2[n][0] + bi, acc2[n][1] + bi,
                               acc2[n][2] + bi, acc2[n][3] + bi);
        *reinterpret_cast<float4*>(
            out + (size_t)(b * 64 + oc) * HWc + gy * 128 + bx * 16 + lh * 4) = v;
    }
}

extern "C" void kernel_launch(void* const* d_in, const int* in_sizes, int n_in,
                              void* d_out, int out_size, void* d_ws, size_t ws_size,
                              hipStream_t stream) {
    const float* x      = (const float*)d_in[0];
    const float* w_off  = (const float*)d_in[1];
    const float* cob    = (const float*)d_in[2];
    const float* weight = (const float*)d_in[3];
    const float* bias   = (const float*)d_in[4];
    float* out = (float*)d_out;
    if (ws_size < WS_NEEDED) return;

    char* ws = (char*)d_ws;
    __half* xT  = (__half*)ws;
    __half* wB1 = (__half*)(ws + WB1_OFF);
    __half* wM2 = (__half*)(ws + WM_OFF);

    prep_all<<<1777, 256, 0, stream>>>(x, w_off, weight, xT, wB1, wM2);
    dcn_fused_k<<<dim3(8, 16, 2), 512, 0, stream>>>(xT, wB1, cob, wM2, bias, out);
}